// Round 1
// baseline (46.040 us; speedup 1.0000x reference)
//
#include <hip/hip_runtime.h>

#define SURV_EPS 1e-7f
#define T_BINS 32
#define NBLOCKS 2048
#define NTHREADS 256

// Kernel 1: grid-stride over float4 chunks of preds; per-block double partial sums.
__global__ __launch_bounds__(NTHREADS) void surv_loss_partial(
    const float* __restrict__ preds,
    const int* __restrict__ targets,
    double* __restrict__ partial,
    int n_rows)
{
    const int n_chunks = n_rows * (T_BINS / 4);  // 8 chunks per row
    double acc = 0.0;

    for (int i = blockIdx.x * blockDim.x + threadIdx.x; i < n_chunks;
         i += gridDim.x * blockDim.x) {
        const int r  = i >> 3;        // row
        const int c  = i & 7;         // chunk within row
        const int jb = c << 2;        // first bin index of this chunk

        const float4 p = reinterpret_cast<const float4*>(preds)[i];
        // 8 consecutive lanes share a row -> same cache line, L1 broadcast
        const int2 tg = reinterpret_cast<const int2*>(targets)[r];
        int t_i = tg.x;
        t_i = t_i < 1 ? 1 : (t_i > T_BINS ? T_BINS : t_i);
        const bool evb = (tg.y != 0);

        float pv[4] = {p.x, p.y, p.z, p.w};
        float s = 0.0f;
#pragma unroll
        for (int k = 0; k < 4; ++k) {
            const int j = jb + k;
            const float h = fminf(fmaxf(pv[k], SURV_EPS), 1.0f - SURV_EPS);
            const float x = evb ? h : fmaxf(1.0f - h, SURV_EPS);
            const bool use = evb ? (j >= t_i - 1) : (j < t_i);
            if (use) s -= logf(x);
        }
        acc += (double)s;
    }

    __shared__ double sm[NTHREADS];
    const int tid = threadIdx.x;
    sm[tid] = acc;
    __syncthreads();
#pragma unroll
    for (int sN = NTHREADS / 2; sN > 0; sN >>= 1) {
        if (tid < sN) sm[tid] += sm[tid + sN];
        __syncthreads();
    }
    if (tid == 0) partial[blockIdx.x] = sm[0];
}

// Kernel 2: single block reduces the per-block partials, writes mean as f32.
__global__ __launch_bounds__(NTHREADS) void surv_loss_finish(
    const double* __restrict__ partial,
    float* __restrict__ out,
    int n_partials,
    int n_rows)
{
    const int tid = threadIdx.x;
    double acc = 0.0;
    for (int i = tid; i < n_partials; i += NTHREADS) acc += partial[i];

    __shared__ double sm[NTHREADS];
    sm[tid] = acc;
    __syncthreads();
#pragma unroll
    for (int sN = NTHREADS / 2; sN > 0; sN >>= 1) {
        if (tid < sN) sm[tid] += sm[tid + sN];
        __syncthreads();
    }
    if (tid == 0) out[0] = (float)(sm[0] / (double)n_rows);
}

extern "C" void kernel_launch(void* const* d_in, const int* in_sizes, int n_in,
                              void* d_out, int out_size, void* d_ws, size_t ws_size,
                              hipStream_t stream) {
    const float* preds   = (const float*)d_in[0];
    const int*   targets = (const int*)d_in[1];
    const int n_rows = in_sizes[0] / T_BINS;   // 1,500,000

    double* partial = (double*)d_ws;           // NBLOCKS doubles = 16 KiB
    float*  out     = (float*)d_out;

    surv_loss_partial<<<NBLOCKS, NTHREADS, 0, stream>>>(preds, targets, partial, n_rows);
    surv_loss_finish<<<1, NTHREADS, 0, stream>>>(partial, out, NBLOCKS, n_rows);
}

// Round 2
// 38.937 us; speedup vs baseline: 1.1824x; 1.1824x over previous
//
#include <hip/hip_runtime.h>

#define SURV_EPS 1e-7f
#define T_BINS 32
#define NBLOCKS 2048
#define NTHREADS 256

// Kernel 1: grid-stride over float4 chunks of preds; per-block double partial sums.
// Per chunk: one __logf of the product of selected terms (log-of-product trick).
__global__ __launch_bounds__(NTHREADS) void surv_loss_partial(
    const float* __restrict__ preds,
    const int* __restrict__ targets,
    double* __restrict__ partial,
    int n_rows)
{
    const int n_chunks = n_rows * (T_BINS / 4);  // 8 chunks per row
    double acc = 0.0;

    for (int i = blockIdx.x * blockDim.x + threadIdx.x; i < n_chunks;
         i += gridDim.x * blockDim.x) {
        const int r  = i >> 3;        // row
        const int jb = (i & 7) << 2;  // first bin index of this chunk

        const float4 p = reinterpret_cast<const float4*>(preds)[i];
        // 8 consecutive lanes share a row -> same cache line, L1 broadcast
        const int2 tg = reinterpret_cast<const int2*>(targets)[r];
        int t_i = tg.x;
        t_i = t_i < 1 ? 1 : (t_i > T_BINS ? T_BINS : t_i);
        const bool evb = (tg.y != 0);
        // used-bin window [lo, hi):  event: [t_i-1, T); censored: [0, t_i)
        const int lo = evb ? (t_i - 1) : 0;
        const int hi = evb ? T_BINS    : t_i;

        const float pv[4] = {p.x, p.y, p.z, p.w};
        float prod = 1.0f;
#pragma unroll
        for (int k = 0; k < 4; ++k) {
            const int j = jb + k;
            const float h = fminf(fmaxf(pv[k], SURV_EPS), 1.0f - SURV_EPS);
            const float x = evb ? h : (1.0f - h);   // both already in [eps, 1-eps]
            const bool use = (j >= lo) & (j < hi);
            prod *= use ? x : 1.0f;
        }
        acc += (double)(-__logf(prod));
    }

    __shared__ double sm[NTHREADS];
    const int tid = threadIdx.x;
    sm[tid] = acc;
    __syncthreads();
#pragma unroll
    for (int sN = NTHREADS / 2; sN > 0; sN >>= 1) {
        if (tid < sN) sm[tid] += sm[tid + sN];
        __syncthreads();
    }
    if (tid == 0) partial[blockIdx.x] = sm[0];
}

// Kernel 2: single block reduces the per-block partials, writes mean as f32.
__global__ __launch_bounds__(NTHREADS) void surv_loss_finish(
    const double* __restrict__ partial,
    float* __restrict__ out,
    int n_partials,
    int n_rows)
{
    const int tid = threadIdx.x;
    double acc = 0.0;
    for (int i = tid; i < n_partials; i += NTHREADS) acc += partial[i];

    __shared__ double sm[NTHREADS];
    sm[tid] = acc;
    __syncthreads();
#pragma unroll
    for (int sN = NTHREADS / 2; sN > 0; sN >>= 1) {
        if (tid < sN) sm[tid] += sm[tid + sN];
        __syncthreads();
    }
    if (tid == 0) out[0] = (float)(sm[0] / (double)n_rows);
}

extern "C" void kernel_launch(void* const* d_in, const int* in_sizes, int n_in,
                              void* d_out, int out_size, void* d_ws, size_t ws_size,
                              hipStream_t stream) {
    const float* preds   = (const float*)d_in[0];
    const int*   targets = (const int*)d_in[1];
    const int n_rows = in_sizes[0] / T_BINS;   // 1,500,000

    double* partial = (double*)d_ws;           // NBLOCKS doubles = 16 KiB
    float*  out     = (float*)d_out;

    surv_loss_partial<<<NBLOCKS, NTHREADS, 0, stream>>>(preds, targets, partial, n_rows);
    surv_loss_finish<<<1, NTHREADS, 0, stream>>>(partial, out, NBLOCKS, n_rows);
}